// Round 2
// baseline (252.138 us; speedup 1.0000x reference)
//
#include <hip/hip_runtime.h>
#include <math.h>

#define BB 256
#define VV 400000
#define NR 500
#define D1 128
#define D2 128
#define PP 64
#define KK 30
#define TT 20
#define XSTRIDE 32   // pad x rows to 128 B for aligned s_load_dwordx16
#define BN_EPS 1e-5f
// 1/sqrt(K*T) = 1/sqrt(600)
#define FACTOR 0.04082482904638631f

// ---------------- Kernel 1: compute x[B][K] into workspace (stride 32) -----
// One block (1 wave, 64 threads) per batch row.
__global__ __launch_bounds__(64) void lowfer_stage1(
    const int* __restrict__ e1_idx, const int* __restrict__ r_idx,
    const float* __restrict__ E, const float* __restrict__ R,
    const float* __restrict__ proj, const int* __restrict__ idx,
    const float* __restrict__ g0, const float* __restrict__ b0,
    const float* __restrict__ m0, const float* __restrict__ v0,
    const float* __restrict__ g1, const float* __restrict__ b1,
    const float* __restrict__ m1, const float* __restrict__ v1,
    float* __restrict__ xw)
{
    __shared__ float e1s[D1];
    __shared__ float rs[D1];
    __shared__ float ses[PP];
    __shared__ float srs[PP];
    __shared__ float xsq[KK];

    const int tid = threadIdx.x;
    const int row = blockIdx.x;

    const int eix = e1_idx[row];
    const int rix = r_idx[row];

    // Load e1 row (with BN0) and r row into LDS. 64 threads x 2 elems.
    for (int j = tid; j < D1; j += 64) {
        float ev = E[(size_t)eix * D1 + j];
        e1s[j] = (ev - m0[j]) * rsqrtf(v0[j] + BN_EPS) * g0[j] + b0[j];
        rs[j]  = R[(size_t)rix * D2 + j];
    }
    __syncthreads();

    // se[p], sr[p] for p = tid (P == 64 == wave size). proj load is coalesced.
    float se = 0.f, sr = 0.f;
#pragma unroll 4
    for (int d = 0; d < D1; ++d) {
        float pv = proj[d * PP + tid];
        se += e1s[d] * pv;
        sr += rs[d]  * pv;
    }
    ses[tid] = se;
    srs[tid] = sr;
    __syncthreads();

    // y[k] for k = tid < K, then signed sqrt.
    float xv = 0.f;
    if (tid < KK) {
        float y = 0.f;
        for (int t = 0; t < TT; ++t) {
            int i0 = idx[(tid * TT + t) * 2 + 0];
            int i1 = idx[(tid * TT + t) * 2 + 1];
            y += ses[i0] * srs[i1];
        }
        y *= FACTOR;
        float s = (y > 0.f) ? 1.f : ((y < 0.f) ? -1.f : 0.f);
        xv = s * sqrtf(fabsf(y) + 1e-12f);
        xsq[tid] = xv * xv;
    }
    __syncthreads();

    if (tid < KK) {
        float ss = 0.f;
#pragma unroll
        for (int k = 0; k < KK; ++k) ss += xsq[k];   // broadcast LDS reads
        float nrm = fmaxf(sqrtf(ss), 1e-12f);
        float xn = xv / nrm;
        xn = (xn - m1[tid]) * rsqrtf(v1[tid] + BN_EPS) * g1[tid] + b1[tid];
        xw[row * XSTRIDE + tid] = xn;
    }
}

// ---------------- Kernel 2: out[b][v] = sigmoid(x[b] . E[v][0:K]) ----------
// One thread per v column. x is block-uniform -> scalar (s_load) path:
// no LDS, no per-lane broadcast traffic. v_fmac takes one SGPR operand.
__global__ __launch_bounds__(256) void lowfer_stage2(
    const float* __restrict__ E, const float* __restrict__ xw,
    float* __restrict__ out)
{
    const int tid = threadIdx.x;
    const int v = blockIdx.x * 256 + tid;
    const bool valid = (v < VV);
    const int vc = valid ? v : (VV - 1);   // clamp so loads are always legal

    // Load E[vc][0:30] into registers: 7 x float4 + 1 x float2 (row 512B-aligned).
    float e[KK];
    {
        const float4* Ep = (const float4*)(E + (size_t)vc * D1);
#pragma unroll
        for (int q = 0; q < 7; ++q) {
            float4 t4 = Ep[q];
            e[q * 4 + 0] = t4.x; e[q * 4 + 1] = t4.y;
            e[q * 4 + 2] = t4.z; e[q * 4 + 3] = t4.w;
        }
        float2 t2 = *(const float2*)(E + (size_t)vc * D1 + 28);
        e[28] = t2.x; e[29] = t2.y;
    }

    for (int b = 0; b < BB; ++b) {
        const float* __restrict__ xr = xw + (size_t)b * XSTRIDE; // uniform addr
        // 4 partial accumulators to break the FMA dependence chain.
        float a0 = 0.f, a1 = 0.f, a2 = 0.f, a3 = 0.f;
#pragma unroll
        for (int k = 0; k < 28; k += 4) {
            a0 += xr[k + 0] * e[k + 0];
            a1 += xr[k + 1] * e[k + 1];
            a2 += xr[k + 2] * e[k + 2];
            a3 += xr[k + 3] * e[k + 3];
        }
        a0 += xr[28] * e[28];
        a1 += xr[29] * e[29];
        float acc = (a0 + a1) + (a2 + a3);
        float sg = 1.f / (1.f + __expf(-acc));
        if (valid)
            __builtin_nontemporal_store(sg, &out[(size_t)b * VV + v]);
    }
}

extern "C" void kernel_launch(void* const* d_in, const int* in_sizes, int n_in,
                              void* d_out, int out_size, void* d_ws, size_t ws_size,
                              hipStream_t stream) {
    const int*   e1_idx = (const int*)  d_in[0];
    const int*   r_idx  = (const int*)  d_in[1];
    const float* E      = (const float*)d_in[2];
    const float* R      = (const float*)d_in[3];
    const float* proj   = (const float*)d_in[4];
    const int*   idx    = (const int*)  d_in[5];
    const float* g0     = (const float*)d_in[6];
    const float* b0     = (const float*)d_in[7];
    const float* m0     = (const float*)d_in[8];
    const float* v0     = (const float*)d_in[9];
    const float* g1     = (const float*)d_in[10];
    const float* b1     = (const float*)d_in[11];
    const float* m1     = (const float*)d_in[12];
    const float* v1     = (const float*)d_in[13];
    float* out = (float*)d_out;
    float* xw  = (float*)d_ws;   // B*32 floats = 32 KB

    lowfer_stage1<<<BB, 64, 0, stream>>>(e1_idx, r_idx, E, R, proj, idx,
                                         g0, b0, m0, v0, g1, b1, m1, v1, xw);

    int grid2 = (VV + 255) / 256;
    lowfer_stage2<<<grid2, 256, 0, stream>>>(E, xw, out);
}

// Round 3
// 142.764 us; speedup vs baseline: 1.7661x; 1.7661x over previous
//
#include <hip/hip_runtime.h>
#include <math.h>

#define BB 256
#define VV 400000
#define NR 500
#define D1 128
#define D2 128
#define PP 64
#define KK 30
#define TT 20
#define XSTRIDE 32   // x rows padded to 32 bf16 (64 B)
#define BN_EPS 1e-5f
// 1/sqrt(K*T) = 1/sqrt(600)
#define FACTOR 0.04082482904638631f

typedef __attribute__((ext_vector_type(8))) short bf16x8;
typedef __attribute__((ext_vector_type(4))) float f32x4;

static __device__ inline unsigned short f2bf(float f) {
    union { float f; unsigned u; } x; x.f = f;
    unsigned r = x.u + 0x7fff + ((x.u >> 16) & 1);   // RNE
    return (unsigned short)(r >> 16);
}

// ---------------- Kernel 1: compute x[B][K] -> bf16, pad to 32 -------------
// One block (1 wave, 64 threads) per batch row.
__global__ __launch_bounds__(64) void lowfer_stage1(
    const int* __restrict__ e1_idx, const int* __restrict__ r_idx,
    const float* __restrict__ E, const float* __restrict__ R,
    const float* __restrict__ proj, const int* __restrict__ idx,
    const float* __restrict__ g0, const float* __restrict__ b0,
    const float* __restrict__ m0, const float* __restrict__ v0,
    const float* __restrict__ g1, const float* __restrict__ b1,
    const float* __restrict__ m1, const float* __restrict__ v1,
    unsigned short* __restrict__ xwb)
{
    __shared__ float e1s[D1];
    __shared__ float rs[D1];
    __shared__ float ses[PP];
    __shared__ float srs[PP];
    __shared__ float xsq[KK];

    const int tid = threadIdx.x;
    const int row = blockIdx.x;

    const int eix = e1_idx[row];
    const int rix = r_idx[row];

    for (int j = tid; j < D1; j += 64) {
        float ev = E[(size_t)eix * D1 + j];
        e1s[j] = (ev - m0[j]) * rsqrtf(v0[j] + BN_EPS) * g0[j] + b0[j];
        rs[j]  = R[(size_t)rix * D2 + j];
    }
    __syncthreads();

    float se = 0.f, sr = 0.f;
#pragma unroll 4
    for (int d = 0; d < D1; ++d) {
        float pv = proj[d * PP + tid];
        se += e1s[d] * pv;
        sr += rs[d]  * pv;
    }
    ses[tid] = se;
    srs[tid] = sr;
    __syncthreads();

    float xv = 0.f;
    if (tid < KK) {
        float y = 0.f;
        for (int t = 0; t < TT; ++t) {
            int i0 = idx[(tid * TT + t) * 2 + 0];
            int i1 = idx[(tid * TT + t) * 2 + 1];
            y += ses[i0] * srs[i1];
        }
        y *= FACTOR;
        float s = (y > 0.f) ? 1.f : ((y < 0.f) ? -1.f : 0.f);
        xv = s * sqrtf(fabsf(y) + 1e-12f);
        xsq[tid] = xv * xv;
    }
    __syncthreads();

    if (tid < XSTRIDE) {
        float val = 0.f;
        if (tid < KK) {
            float ss = 0.f;
#pragma unroll
            for (int k = 0; k < KK; ++k) ss += xsq[k];
            float nrm = fmaxf(sqrtf(ss), 1e-12f);
            float xn = xv / nrm;
            val = (xn - m1[tid]) * rsqrtf(v1[tid] + BN_EPS) * g1[tid] + b1[tid];
        }
        xwb[row * XSTRIDE + tid] = f2bf(val);
    }
}

// ---------------- Kernel 2: out = sigmoid(x @ E30^T) via MFMA --------------
// Block = 256 thr (4 waves). Each wave owns 16 v-cols, computes all 256
// b-rows as 16 MFMA tiles (16x16x32 bf16, K one-shot). No LDS, no barriers.
__global__ __launch_bounds__(256) void lowfer_stage2(
    const float* __restrict__ E, const unsigned short* __restrict__ xwb,
    float* __restrict__ out)
{
    const int wid  = threadIdx.x >> 6;
    const int lane = threadIdx.x & 63;
    const int col  = lane & 15;     // v within tile / C col
    const int kq   = lane >> 4;     // k quarter (8 k each)
    const int v    = blockIdx.x * 64 + wid * 16 + col;   // grid covers VV exactly

    // B fragment: E[v][kq*8 .. kq*8+7] -> bf16; zero k=30,31.
    const float* Ep = E + (size_t)v * D1 + kq * 8;
    float4 t0 = *(const float4*)(Ep);
    float4 t1 = *(const float4*)(Ep + 4);
    if (kq == 3) { t1.z = 0.f; t1.w = 0.f; }
    bf16x8 bf;
    bf[0] = (short)f2bf(t0.x); bf[1] = (short)f2bf(t0.y);
    bf[2] = (short)f2bf(t0.z); bf[3] = (short)f2bf(t0.w);
    bf[4] = (short)f2bf(t1.x); bf[5] = (short)f2bf(t1.y);
    bf[6] = (short)f2bf(t1.z); bf[7] = (short)f2bf(t1.w);

    const f32x4 zero = {0.f, 0.f, 0.f, 0.f};

#pragma unroll
    for (int bt = 0; bt < 16; ++bt) {
        // A fragment: x[bt*16 + col][kq*8 ..] (bf16, 64 B rows, 16 B aligned)
        bf16x8 af = *(const bf16x8*)(xwb + (bt * 16 + col) * XSTRIDE + kq * 8);
        f32x4 acc = __builtin_amdgcn_mfma_f32_16x16x32_bf16(af, bf, zero, 0, 0, 0);
        // C/D layout: col = lane&15 (=v), row = kq*4 + i
#pragma unroll
        for (int i = 0; i < 4; ++i) {
            int row = bt * 16 + kq * 4 + i;
            float a = acc[i];
            float sg = __builtin_amdgcn_rcpf(1.f + __expf(-a));
            __builtin_nontemporal_store(sg, &out[(size_t)row * VV + v]);
        }
    }
}

extern "C" void kernel_launch(void* const* d_in, const int* in_sizes, int n_in,
                              void* d_out, int out_size, void* d_ws, size_t ws_size,
                              hipStream_t stream) {
    const int*   e1_idx = (const int*)  d_in[0];
    const int*   r_idx  = (const int*)  d_in[1];
    const float* E      = (const float*)d_in[2];
    const float* R      = (const float*)d_in[3];
    const float* proj   = (const float*)d_in[4];
    const int*   idx    = (const int*)  d_in[5];
    const float* g0     = (const float*)d_in[6];
    const float* b0     = (const float*)d_in[7];
    const float* m0     = (const float*)d_in[8];
    const float* v0     = (const float*)d_in[9];
    const float* g1     = (const float*)d_in[10];
    const float* b1     = (const float*)d_in[11];
    const float* m1     = (const float*)d_in[12];
    const float* v1     = (const float*)d_in[13];
    float* out = (float*)d_out;
    unsigned short* xwb = (unsigned short*)d_ws;   // 256*32 bf16 = 16 KB

    lowfer_stage1<<<BB, 64, 0, stream>>>(e1_idx, r_idx, E, R, proj, idx,
                                         g0, b0, m0, v0, g1, b1, m1, v1, xwb);

    lowfer_stage2<<<VV / 64, 256, 0, stream>>>(E, xwb, out);
}

// Round 5
// 100.603 us; speedup vs baseline: 2.5063x; 1.4191x over previous
//
#include <hip/hip_runtime.h>
#include <math.h>

#define BB 256
#define VV 400000
#define NR 500
#define D1 128
#define D2 128
#define PP 64
#define KK 30
#define TT 20
#define XSTRIDE 32   // x rows padded to 32 bf16 (64 B)
#define BN_EPS 1e-5f
// 1/sqrt(K*T) = 1/sqrt(600)
#define FACTOR 0.04082482904638631f

#define VB 128       // v-columns per block in stage2
#define LSTR 132     // LDS tile row stride in dwords (128 + 4 pad)

typedef __attribute__((ext_vector_type(8))) short bf16x8;
typedef __attribute__((ext_vector_type(4))) float f32x4;
typedef __attribute__((ext_vector_type(2))) float f32x2;

static __device__ inline unsigned short f2bf(float f) {
    union { float f; unsigned u; } x; x.f = f;
    unsigned r = x.u + 0x7fff + ((x.u >> 16) & 1);   // RNE
    return (unsigned short)(r >> 16);
}

// ---------------- Kernel 1: compute x[B][K] -> bf16, pad to 32 -------------
// One block (1 wave, 64 threads) per batch row.
__global__ __launch_bounds__(64) void lowfer_stage1(
    const int* __restrict__ e1_idx, const int* __restrict__ r_idx,
    const float* __restrict__ E, const float* __restrict__ R,
    const float* __restrict__ proj, const int* __restrict__ idx,
    const float* __restrict__ g0, const float* __restrict__ b0,
    const float* __restrict__ m0, const float* __restrict__ v0,
    const float* __restrict__ g1, const float* __restrict__ b1,
    const float* __restrict__ m1, const float* __restrict__ v1,
    unsigned short* __restrict__ xwb)
{
    __shared__ float e1s[D1];
    __shared__ float rs[D1];
    __shared__ float ses[PP];
    __shared__ float srs[PP];
    __shared__ float xsq[KK];

    const int tid = threadIdx.x;
    const int row = blockIdx.x;

    const int eix = e1_idx[row];
    const int rix = r_idx[row];

    for (int j = tid; j < D1; j += 64) {
        float ev = E[(size_t)eix * D1 + j];
        e1s[j] = (ev - m0[j]) * rsqrtf(v0[j] + BN_EPS) * g0[j] + b0[j];
        rs[j]  = R[(size_t)rix * D2 + j];
    }
    __syncthreads();

    float se = 0.f, sr = 0.f;
#pragma unroll 4
    for (int d = 0; d < D1; ++d) {
        float pv = proj[d * PP + tid];
        se += e1s[d] * pv;
        sr += rs[d]  * pv;
    }
    ses[tid] = se;
    srs[tid] = sr;
    __syncthreads();

    float xv = 0.f;
    if (tid < KK) {
        float y = 0.f;
        for (int t = 0; t < TT; ++t) {
            int i0 = idx[(tid * TT + t) * 2 + 0];
            int i1 = idx[(tid * TT + t) * 2 + 1];
            y += ses[i0] * srs[i1];
        }
        y *= FACTOR;
        float s = (y > 0.f) ? 1.f : ((y < 0.f) ? -1.f : 0.f);
        xv = s * sqrtf(fabsf(y) + 1e-12f);
        xsq[tid] = xv * xv;
    }
    __syncthreads();

    if (tid < XSTRIDE) {
        float val = 0.f;
        if (tid < KK) {
            float ss = 0.f;
#pragma unroll
            for (int k = 0; k < KK; ++k) ss += xsq[k];
            float nrm = fmaxf(sqrtf(ss), 1e-12f);
            float xn = xv / nrm;
            val = (xn - m1[tid]) * rsqrtf(v1[tid] + BN_EPS) * g1[tid] + b1[tid];
        }
        xwb[row * XSTRIDE + tid] = f2bf(val);
    }
}

// ---------------- Kernel 2: out = sigmoid(x @ E30^T) via MFMA --------------
// Block = 256 thr (4 waves) covering 128 v-cols x all 256 b-rows.
// Each wave owns 32 v (two 16x16 subtiles). Per b-tile: 2 MFMA, sigmoid in
// registers, transpose via LDS (double-buffered), then each wave stores one
// FULL output row segment per instruction: 512 B contiguous dwordx2 stores.
__global__ __launch_bounds__(256) void lowfer_stage2(
    const float* __restrict__ E, const unsigned short* __restrict__ xwb,
    float* __restrict__ out)
{
    __shared__ float tile[2][16][LSTR];   // 2 * 16 * 132 * 4 B = 16.5 KB

    const int wid  = threadIdx.x >> 6;
    const int lane = threadIdx.x & 63;
    const int col  = lane & 15;     // v within subtile / C col
    const int kq   = lane >> 4;     // k quarter (8 k each)
    const int vbase = blockIdx.x * VB;
    const int v0 = vbase + wid * 32 + col;   // wave's first v-subtile

    // B fragments: E[v][kq*8 ..] -> bf16 for subtiles v0 and v0+16; zero k>=30.
    bf16x8 bf0, bf1;
    {
        const float* Ep0 = E + (size_t)v0 * D1 + kq * 8;
        float4 a0 = *(const float4*)(Ep0);
        float4 a1 = *(const float4*)(Ep0 + 4);
        const float* Ep1 = E + (size_t)(v0 + 16) * D1 + kq * 8;
        float4 c0 = *(const float4*)(Ep1);
        float4 c1 = *(const float4*)(Ep1 + 4);
        if (kq == 3) { a1.z = 0.f; a1.w = 0.f; c1.z = 0.f; c1.w = 0.f; }
        bf0[0] = (short)f2bf(a0.x); bf0[1] = (short)f2bf(a0.y);
        bf0[2] = (short)f2bf(a0.z); bf0[3] = (short)f2bf(a0.w);
        bf0[4] = (short)f2bf(a1.x); bf0[5] = (short)f2bf(a1.y);
        bf0[6] = (short)f2bf(a1.z); bf0[7] = (short)f2bf(a1.w);
        bf1[0] = (short)f2bf(c0.x); bf1[1] = (short)f2bf(c0.y);
        bf1[2] = (short)f2bf(c0.z); bf1[3] = (short)f2bf(c0.w);
        bf1[4] = (short)f2bf(c1.x); bf1[5] = (short)f2bf(c1.y);
        bf1[6] = (short)f2bf(c1.z); bf1[7] = (short)f2bf(c1.w);
    }

    const f32x4 zero = {0.f, 0.f, 0.f, 0.f};

    for (int bt = 0; bt < 16; ++bt) {
        const int buf = bt & 1;
        // A fragment: x[bt*16 + col][kq*8 ..] (bf16, 64 B rows, 16 B aligned)
        bf16x8 af = *(const bf16x8*)(xwb + (bt * 16 + col) * XSTRIDE + kq * 8);
        f32x4 acc0 = __builtin_amdgcn_mfma_f32_16x16x32_bf16(af, bf0, zero, 0, 0, 0);
        f32x4 acc1 = __builtin_amdgcn_mfma_f32_16x16x32_bf16(af, bf1, zero, 0, 0, 0);

        // sigmoid in registers, stash transposed in LDS.
        // C/D layout: col = lane&15 (v), row = kq*4 + i (b within tile).
#pragma unroll
        for (int i = 0; i < 4; ++i) {
            int row = kq * 4 + i;
            tile[buf][row][wid * 32 + col] =
                __builtin_amdgcn_rcpf(1.f + __expf(-acc0[i]));
            tile[buf][row][wid * 32 + 16 + col] =
                __builtin_amdgcn_rcpf(1.f + __expf(-acc1[i]));
        }
        __syncthreads();

        // Store phase: wave wid handles rows wid*4 .. wid*4+3; one full
        // 128-float row segment (512 B contiguous) per store instruction.
#pragma unroll
        for (int r = 0; r < 4; ++r) {
            int row = wid * 4 + r;
            f32x2 d = *(const f32x2*)&tile[buf][row][lane * 2];
            __builtin_nontemporal_store(
                d, (f32x2*)&out[(size_t)(bt * 16 + row) * VV + vbase + lane * 2]);
        }
        // no second barrier: next iteration writes tile[buf^1]; the WAR on
        // tile[buf] is separated by the next iteration's __syncthreads().
    }
}

extern "C" void kernel_launch(void* const* d_in, const int* in_sizes, int n_in,
                              void* d_out, int out_size, void* d_ws, size_t ws_size,
                              hipStream_t stream) {
    const int*   e1_idx = (const int*)  d_in[0];
    const int*   r_idx  = (const int*)  d_in[1];
    const float* E      = (const float*)d_in[2];
    const float* R      = (const float*)d_in[3];
    const float* proj   = (const float*)d_in[4];
    const int*   idx    = (const int*)  d_in[5];
    const float* g0     = (const float*)d_in[6];
    const float* b0     = (const float*)d_in[7];
    const float* m0     = (const float*)d_in[8];
    const float* v0     = (const float*)d_in[9];
    const float* g1     = (const float*)d_in[10];
    const float* b1     = (const float*)d_in[11];
    const float* m1     = (const float*)d_in[12];
    const float* v1     = (const float*)d_in[13];
    float* out = (float*)d_out;
    unsigned short* xwb = (unsigned short*)d_ws;   // 256*32 bf16 = 16 KB

    lowfer_stage1<<<BB, 64, 0, stream>>>(e1_idx, r_idx, E, R, proj, idx,
                                         g0, b0, m0, v0, g1, b1, m1, v1, xwb);

    lowfer_stage2<<<VV / VB, 256, 0, stream>>>(E, xwb, out);
}